// Round 7
// baseline (2959.166 us; speedup 1.0000x reference)
//
#include <hip/hip_runtime.h>
#include <hip/hip_bf16.h>

typedef unsigned short u16;
typedef __attribute__((ext_vector_type(8))) __bf16 bf16x8;
typedef __attribute__((ext_vector_type(4))) float f32x4;
typedef __attribute__((ext_vector_type(4))) unsigned int u32x4;

#define BB 4096
#define TT 19
#define INP 17
#define HH 1024

__device__ __forceinline__ u16 f2bfu(float f) {
    __hip_bfloat16 b = __float2bfloat16(f);
    return __builtin_bit_cast(unsigned short, b);
}
__device__ __forceinline__ float bfu2f(u16 u) {
    unsigned int x = ((unsigned int)u) << 16;
    return __builtin_bit_cast(float, x);
}
__device__ __forceinline__ float fast_sigmoid(float x) {
    return 1.f / (1.f + __expf(-x));
}
__device__ __forceinline__ float fast_tanh(float x) {
    float e = __expf(2.f * x);
    return (e - 1.f) / (e + 1.f);
}
__device__ __forceinline__ bf16x8 ld16(const u16* p) {
    return __builtin_bit_cast(bf16x8, *(const u32x4*)p);
}

// ---------------- prep kernels ----------------
// grid MUST be 2048: 2048*256*8 == 4*HH*HH elements exactly.
__global__ void prep_w(const float* __restrict__ W, u16* __restrict__ whi) {
    int idx = (blockIdx.x * 256 + threadIdx.x) * 8;
#pragma unroll
    for (int e = 0; e < 8; ++e) whi[idx + e] = f2bfu(W[idx + e]);
}

__global__ void prep_misc(const float* __restrict__ Wih, const float* __restrict__ bih,
                          const float* __restrict__ bhh, const float* __restrict__ Wlin,
                          u16* __restrict__ wihp, float* __restrict__ bias,
                          u16* __restrict__ wlin_dst) {
    int idx = blockIdx.x * 256 + threadIdx.x;  // 0 .. 131071
    int r = idx >> 5, c = idx & 31;
    wihp[idx] = (c < INP) ? f2bfu(Wih[r * INP + c]) : (u16)0;
    if (idx < 4 * HH) bias[idx] = bih[idx] + bhh[idx];
    if (idx < INP * HH) wlin_dst[idx] = f2bfu(Wlin[idx]);  // rows 4096..4112 of whi_ext
}

__global__ void prep_x(const float* __restrict__ x, u16* __restrict__ xpad) {
    int idx = blockIdx.x * 256 + threadIdx.x;  // 0 .. 19*4096*32-1
    int c = idx & 31;
    int rb = idx >> 5;       // t*4096 + b
    int t = rb >> 12;
    int b = rb & 4095;
    xpad[idx] = (c < INP) ? f2bfu(x[((size_t)b * TT + t) * INP + c]) : (u16)0;
}

// ---------------- fused gates + cell (+folded projection) kernel ----------
// 1-wave (64-thread) blocks; grid 4160 = 64 mt x 65 ntq. No LDS, no barriers:
// A (h rows) and B (W rows) fragments are loaded straight from L2/L3.
// ntq 0..63: gates tile (16 cols x 4 gates) -> LSTM cell -> h/c.
// ntq == 64: B rows come from appended [W_lin; 0] rows of whi_ext, so acc is
//            out_{t-1} = h_t @ W_lin^T; written directly (no atomics).
// Tail dispatch (proj_force=1, t=19, grid 64) produces out_18.
__global__ __launch_bounds__(64, 4) void lstm_fused(
    const u16* __restrict__ h_in, u16* __restrict__ h_out,
    float* __restrict__ c_buf, const u16* __restrict__ whi,
    const u16* __restrict__ wihp, const float* __restrict__ bias,
    const u16* __restrict__ xpad, const float* __restrict__ blin,
    float* __restrict__ outp, float* __restrict__ h_fin,
    int t, int is_last, int proj_force)
{
    const int lane = threadIdx.x;
    const int r16 = lane & 15;
    const int s4 = lane >> 4;
    int ntq, mt;
    if (proj_force) { ntq = 64; mt = blockIdx.x; }
    else            { ntq = blockIdx.x >> 6; mt = blockIdx.x & 63; }
    const int m0 = mt * 64;

    // B row indices in whi_ext (4352 rows x 1024)
    int brow[4];
#pragma unroll
    for (int g = 0; g < 4; ++g)
        brow[g] = (ntq < 64) ? (g * HH + ntq * 16 + r16) : (4 * HH + g * 16 + r16);

    const u16* ap[4];
#pragma unroll
    for (int mf = 0; mf < 4; ++mf)
        ap[mf] = h_in + (size_t)(m0 + mf * 16 + r16) * HH + s4 * 8;
    const u16* bp[4];
#pragma unroll
    for (int g = 0; g < 4; ++g)
        bp[g] = whi + (size_t)brow[g] * HH + s4 * 8;

    f32x4 acc[4][4];
#pragma unroll
    for (int mf = 0; mf < 4; ++mf)
#pragma unroll
        for (int g = 0; g < 4; ++g) acc[mf][g] = (f32x4){0.f, 0.f, 0.f, 0.f};

    bf16x8 a[4], b[4];

    // ---- step 0: x @ W_ih^T (K padded 17->32; proj rows are zero) ----
    {
        const u16* xa = xpad + ((size_t)t * BB + m0 + r16) * 32 + s4 * 8;
#pragma unroll
        for (int mf = 0; mf < 4; ++mf) a[mf] = ld16(xa + (size_t)mf * 16 * 32);
#pragma unroll
        for (int g = 0; g < 4; ++g) b[g] = ld16(wihp + (size_t)brow[g] * 32 + s4 * 8);
#pragma unroll
        for (int g = 0; g < 4; ++g)
#pragma unroll
            for (int mf = 0; mf < 4; ++mf)
                acc[mf][g] = __builtin_amdgcn_mfma_f32_16x16x32_bf16(a[mf], b[g], acc[mf][g], 0, 0, 0);
    }

    // ---- h @ W^T: K = 1024 in 32 chunks; barrier-free, compiler-pipelined --
#pragma unroll 2
    for (int kc = 0; kc < HH; kc += 32) {
#pragma unroll
        for (int mf = 0; mf < 4; ++mf) a[mf] = ld16(ap[mf] + kc);
#pragma unroll
        for (int g = 0; g < 4; ++g) b[g] = ld16(bp[g] + kc);
#pragma unroll
        for (int g = 0; g < 4; ++g)
#pragma unroll
            for (int mf = 0; mf < 4; ++mf)
                acc[mf][g] = __builtin_amdgcn_mfma_f32_16x16x32_bf16(a[mf], b[g], acc[mf][g], 0, 0, 0);
    }

    // ---- epilogue ----
    if (ntq == 64) {
        if (t == 0) return;               // out_{-1} doesn't exist
#pragma unroll
        for (int mf = 0; mf < 4; ++mf)
#pragma unroll
            for (int j = 0; j < 4; ++j) {
                int br = m0 + mf * 16 + s4 * 4 + j;
#pragma unroll
                for (int g = 0; g < 4; ++g) {
                    int col = g * 16 + r16;
                    if (col < INP)
                        __builtin_nontemporal_store(
                            acc[mf][g][j] + blin[col],
                            &outp[((size_t)br * TT + (t - 1)) * INP + col]);
                }
            }
        return;
    }

    const int n = ntq * 16 + r16;
    const float bi  = bias[n];
    const float bf_ = bias[HH + n];
    const float bg  = bias[2 * HH + n];
    const float bo  = bias[3 * HH + n];
#pragma unroll
    for (int mf = 0; mf < 4; ++mf)
#pragma unroll
        for (int j = 0; j < 4; ++j) {
            int br = m0 + mf * 16 + s4 * 4 + j;
            float iv = fast_sigmoid(acc[mf][0][j] + bi);
            float fv = fast_sigmoid(acc[mf][1][j] + bf_);
            float gv = fast_tanh(acc[mf][2][j] + bg);
            float ov = fast_sigmoid(acc[mf][3][j] + bo);
            size_t ci = (size_t)br * HH + n;
            float cold = __builtin_nontemporal_load(&c_buf[ci]);
            float cnew = fv * cold + iv * gv;
            float hnew = ov * fast_tanh(cnew);
            __builtin_nontemporal_store(cnew, &c_buf[ci]);
            h_out[ci] = f2bfu(hnew);
            if (is_last) __builtin_nontemporal_store(hnew, &h_fin[ci]);
        }
}

// ---------------- launch ----------------
extern "C" void kernel_launch(void* const* d_in, const int* in_sizes, int n_in,
                              void* d_out, int out_size, void* d_ws, size_t ws_size,
                              hipStream_t stream)
{
    const float* x    = (const float*)d_in[0];
    const float* Wih  = (const float*)d_in[1];
    const float* Whh  = (const float*)d_in[2];
    const float* bih  = (const float*)d_in[3];
    const float* bhh  = (const float*)d_in[4];
    const float* Wlin = (const float*)d_in[5];
    const float* blin = (const float*)d_in[6];
    float* out = (float*)d_out;

    char* ws = (char*)d_ws;
    u16* hb0      = (u16*)(ws);                    //  8,388,608 B
    u16* hb1      = (u16*)(ws +  8388608);         //  8,388,608 B
    u16* xpad     = (u16*)(ws + 16777216);         //  5,242,880 B (20 t-slots)
    u16* whi_ext  = (u16*)(ws + 22020096);         //  8,912,896 B (4352 x 1024)
    u16* wihp_ext = (u16*)(ws + 30932992);         //    278,528 B (4352 x 32)
    float* bias   = (float*)(ws + 31211520);       //     16,384 B

    float* h_fin = out + (size_t)BB * TT * INP;    // h_fin region
    float* c_buf = h_fin + (size_t)BB * HH;        // c_fin region = c state

    hipMemsetAsync(hb0, 0, (size_t)BB * HH * sizeof(u16), stream);
    hipMemsetAsync(c_buf, 0, (size_t)BB * HH * sizeof(float), stream);
    // zero: whi_ext rows 4096..4351, wihp_ext rows 4096..4351, xpad slot 19
    hipMemsetAsync((char*)whi_ext + (size_t)4096 * HH * 2, 0, 256 * HH * 2, stream);
    hipMemsetAsync((char*)wihp_ext + (size_t)4096 * 32 * 2, 0, 256 * 32 * 2, stream);
    hipMemsetAsync((char*)xpad + (size_t)19 * BB * 32 * 2, 0, BB * 32 * 2, stream);

    prep_w<<<2048, 256, 0, stream>>>(Whh, whi_ext);
    prep_misc<<<512, 256, 0, stream>>>(Wih, bih, bhh, Wlin, wihp_ext, bias,
                                       whi_ext + (size_t)4096 * HH);
    prep_x<<<9728, 256, 0, stream>>>(x, xpad);

    for (int t = 0; t < TT; ++t) {
        const u16* hin = (t & 1) ? hb1 : hb0;
        u16* hout = (t & 1) ? hb0 : hb1;
        lstm_fused<<<4160, 64, 0, stream>>>(
            hin, hout, c_buf, whi_ext, wihp_ext, bias, xpad, blin, out,
            h_fin, t, (t == TT - 1) ? 1 : 0, 0);
    }
    // tail: out_18 = h_19 @ W_lin^T + b_lin   (h_19 lives in hb1, t=18 wrote it)
    lstm_fused<<<64, 64, 0, stream>>>(
        hb1, hb0, c_buf, whi_ext, wihp_ext, bias, xpad, blin, out,
        h_fin, TT, 0, 1);
}

// Round 8
// 1386.623 us; speedup vs baseline: 2.1341x; 2.1341x over previous
//
#include <hip/hip_runtime.h>
#include <hip/hip_bf16.h>

typedef unsigned short u16;
typedef __attribute__((ext_vector_type(8))) __bf16 bf16x8;
typedef __attribute__((ext_vector_type(8))) short short8;
typedef __attribute__((ext_vector_type(4))) float f32x4;
typedef __attribute__((ext_vector_type(4))) unsigned int u32x4;

#define BB 4096
#define TT 19
#define INP 17
#define HH 1024
#define NE 4224          // 4096 gate entries + 128 proj entries
#define NT_PROJ 32       // nt index of the projection tile

__device__ __forceinline__ u16 f2bfu(float f) {
    __hip_bfloat16 b = __float2bfloat16(f);
    return __builtin_bit_cast(unsigned short, b);
}
__device__ __forceinline__ float fast_sigmoid(float x) {
    return 1.f / (1.f + __expf(-x));
}
__device__ __forceinline__ float fast_tanh(float x) {
    float e = __expf(2.f * x);
    return (e - 1.f) / (e + 1.f);
}
// 16B-slot swizzle within a 32-elem row (involution)
__device__ __forceinline__ int fsw(int r) { return (r ^ (r >> 2)) & 3; }

// async 16B global -> LDS (linear dest: wave-uniform base + lane*16)
__device__ __forceinline__ void cp16(void* l, const void* g) {
    __builtin_amdgcn_global_load_lds(
        (const __attribute__((address_space(1))) unsigned int*)g,
        (__attribute__((address_space(3))) unsigned int*)l, 16, 0, 0);
}

// ---------------- prep kernels ----------------
// wperm[NE][HH]: permuted W rows. grid MUST be 2112 (2112*256*8 == NE*HH).
__global__ void prep_wperm(const float* __restrict__ Whh, const float* __restrict__ Wlin,
                           u16* __restrict__ wperm) {
    size_t idx = ((size_t)blockIdx.x * 256 + threadIdx.x) * 8;
    int R = (int)(idx >> 10);
    int k = (int)(idx & 1023);
    int nt = R >> 7, r = R & 127;
    const float* src = nullptr;
    if (nt < NT_PROJ) {
        int gate = (r & 63) >> 4;
        int hcol = nt * 32 + ((r >> 6) << 4) + (r & 15);
        src = Whh + ((size_t)(gate * HH + hcol)) * HH + k;
    } else if (r < INP) {
        src = Wlin + (size_t)r * HH + k;
    }
#pragma unroll
    for (int e = 0; e < 8; ++e) wperm[idx + e] = src ? f2bfu(src[e]) : (u16)0;
}

// wxperm[NE][32]: permuted, padded W_ih rows. grid 528 (528*256 == NE*32).
__global__ void prep_wx(const float* __restrict__ Wih, u16* __restrict__ wxperm) {
    int idx = blockIdx.x * 256 + threadIdx.x;
    int R = idx >> 5, k = idx & 31;
    int nt = R >> 7, r = R & 127;
    u16 v = 0;
    if (nt < NT_PROJ && k < INP) {
        int gate = (r & 63) >> 4;
        int hcol = nt * 32 + ((r >> 6) << 4) + (r & 15);
        v = f2bfu(Wih[(size_t)(gate * HH + hcol) * INP + k]);
    }
    wxperm[idx] = v;
}

// bias[4096] = b_ih + b_hh. grid 16.
__global__ void prep_bias(const float* __restrict__ bih, const float* __restrict__ bhh,
                          float* __restrict__ bias) {
    int idx = blockIdx.x * 256 + threadIdx.x;
    bias[idx] = bih[idx] + bhh[idx];
}

// xpad[t][b][32]. grid 9728 (9728*256 == 19*4096*32).
__global__ void prep_x(const float* __restrict__ x, u16* __restrict__ xpad) {
    int idx = blockIdx.x * 256 + threadIdx.x;
    int c = idx & 31;
    int rb = idx >> 5;       // t*4096 + b
    int t = rb >> 12;
    int b = rb & 4095;
    xpad[idx] = (c < INP) ? f2bfu(x[((size_t)b * TT + t) * INP + c]) : (u16)0;
}

// ---------------- fused step kernel (m97-structure GEMM) ----------------
// grid 1056 = 32 mt x 33 nt, 256 threads (4 waves, 2x2 quadrants of 64x64).
// C = [x_pad | h] @ [Wih_perm | W_perm]^T + bias   (128 rows x 128 entries)
// nt < 32 : entries = 4 gates x 32 h-cols -> LSTM cell -> h/c writes.
// nt == 32: entries = [W_lin; 0] rows -> out_{t-1} = h_t @ W_lin^T (+b_lin).
__global__ __launch_bounds__(256, 4) void lstm_step(
    const u16* __restrict__ h_in, u16* __restrict__ h_out,
    float* __restrict__ c_buf, const u16* __restrict__ wperm,
    const u16* __restrict__ wxperm, const float* __restrict__ bias,
    const u16* __restrict__ xpad, const float* __restrict__ blin,
    float* __restrict__ outp, float* __restrict__ h_fin,
    int t, int is_last, int proj_force)
{
    __shared__ u16 sA[128 * 32];   // 8 KB
    __shared__ u16 sB[128 * 32];   // 8 KB

    const int tid = threadIdx.x;
    const int lane = tid & 63;
    const int wv = tid >> 6;
    const int qr = wv >> 1, qc = wv & 1;
    const int r16 = lane & 15, s4 = lane >> 4;

    int mt, nt;
    if (proj_force) { mt = blockIdx.x; nt = NT_PROJ; }
    else {
        int v = (blockIdx.x & 7) * 132 + (blockIdx.x >> 3);  // XCD-chunked, bijective
        nt = v >> 5; mt = v & 31;
    }
    const int m0 = mt * 128;
    if (nt == NT_PROJ && t == 0) return;   // uniform early-out, no barriers yet

    // staging: thread covers slots tid and tid+256; slot -> (row=slot>>2, chunk=slot&3)
    const int row0 = tid >> 2, c0 = tid & 3;
    const int row1 = row0 + 64;
    const int xo0 = (c0 ^ fsw(row0)) * 8;
    const int xo1 = (c0 ^ fsw(row1)) * 8;
    const size_t R0 = (size_t)nt * 128;

    // acc init with bias (col constant across the 4 row-regs of a C/D frag)
    f32x4 acc[4][4];
    if (nt < NT_PROJ) {
        const int n = nt * 32 + qc * 16 + r16;
#pragma unroll
        for (int g = 0; g < 4; ++g) {
            float bv = bias[g * HH + n];
#pragma unroll
            for (int mf = 0; mf < 4; ++mf) acc[mf][g] = (f32x4){bv, bv, bv, bv};
        }
    } else {
#pragma unroll
        for (int nf = 0; nf < 4; ++nf) {
            int e = qc * 64 + nf * 16 + r16;
            float bv = (e < INP) ? blin[e] : 0.f;
#pragma unroll
            for (int mf = 0; mf < 4; ++mf) acc[mf][nf] = (f32x4){bv, bv, bv, bv};
        }
    }

    // fragment read offsets (u16 elem index, swizzled)
    int aoff[4], boff[4];
#pragma unroll
    for (int mf = 0; mf < 4; ++mf) {
        int r = qr * 64 + mf * 16 + r16;
        aoff[mf] = r * 32 + ((s4 ^ fsw(r)) * 8);
    }
#pragma unroll
    for (int nf = 0; nf < 4; ++nf) {
        int r = qc * 64 + nf * 16 + r16;
        boff[nf] = r * 32 + ((s4 ^ fsw(r)) * 8);
    }

    // ---- iter 0: x @ Wih^T (K padded 17->32) ----
    cp16(&sA[tid * 8],         xpad + ((size_t)t * BB + m0 + row0) * 32 + xo0);
    cp16(&sA[(tid + 256) * 8], xpad + ((size_t)t * BB + m0 + row1) * 32 + xo1);
    cp16(&sB[tid * 8],         wxperm + (R0 + row0) * 32 + xo0);
    cp16(&sB[(tid + 256) * 8], wxperm + (R0 + row1) * 32 + xo1);
    __syncthreads();
    {
        bf16x8 a[4], b[4];
#pragma unroll
        for (int mf = 0; mf < 4; ++mf) a[mf] = __builtin_bit_cast(bf16x8, *(const short8*)&sA[aoff[mf]]);
#pragma unroll
        for (int nf = 0; nf < 4; ++nf) b[nf] = __builtin_bit_cast(bf16x8, *(const short8*)&sB[boff[nf]]);
#pragma unroll
        for (int nf = 0; nf < 4; ++nf)
#pragma unroll
            for (int mf = 0; mf < 4; ++mf)
                acc[mf][nf] = __builtin_amdgcn_mfma_f32_16x16x32_bf16(a[mf], b[nf], acc[mf][nf], 0, 0, 0);
    }

    // ---- K-loop: h @ W^T, K = 1024, BK = 32, 2-barrier single-buffered ----
    for (int kc = 0; kc < HH; kc += 32) {
        __syncthreads();   // everyone done reading previous tiles
        cp16(&sA[tid * 8],         h_in + (size_t)(m0 + row0) * HH + kc + xo0);
        cp16(&sA[(tid + 256) * 8], h_in + (size_t)(m0 + row1) * HH + kc + xo1);
        cp16(&sB[tid * 8],         wperm + (R0 + row0) * HH + kc + xo0);
        cp16(&sB[(tid + 256) * 8], wperm + (R0 + row1) * HH + kc + xo1);
        __syncthreads();   // vmcnt drained -> tiles resident

        bf16x8 a[4], b[4];
#pragma unroll
        for (int mf = 0; mf < 4; ++mf) a[mf] = __builtin_bit_cast(bf16x8, *(const short8*)&sA[aoff[mf]]);
#pragma unroll
        for (int nf = 0; nf < 4; ++nf) b[nf] = __builtin_bit_cast(bf16x8, *(const short8*)&sB[boff[nf]]);
#pragma unroll
        for (int nf = 0; nf < 4; ++nf)
#pragma unroll
            for (int mf = 0; mf < 4; ++mf)
                acc[mf][nf] = __builtin_amdgcn_mfma_f32_16x16x32_bf16(a[mf], b[nf], acc[mf][nf], 0, 0, 0);
    }

    // ---- epilogue ----
    if (nt < NT_PROJ) {
        const int n = nt * 32 + qc * 16 + r16;
#pragma unroll
        for (int mf = 0; mf < 4; ++mf)
#pragma unroll
            for (int j = 0; j < 4; ++j) {
                int row = m0 + qr * 64 + mf * 16 + s4 * 4 + j;
                float iv = fast_sigmoid(acc[mf][0][j]);
                float fv = fast_sigmoid(acc[mf][1][j]);
                float gv = fast_tanh(acc[mf][2][j]);
                float ov = fast_sigmoid(acc[mf][3][j]);
                size_t ci = (size_t)row * HH + n;
                float cold = __builtin_nontemporal_load(&c_buf[ci]);
                float cnew = fv * cold + iv * gv;
                float hnew = ov * fast_tanh(cnew);
                __builtin_nontemporal_store(cnew, &c_buf[ci]);
                h_out[ci] = f2bfu(hnew);
                if (is_last) __builtin_nontemporal_store(hnew, &h_fin[ci]);
            }
    } else {
#pragma unroll
        for (int mf = 0; mf < 4; ++mf)
#pragma unroll
            for (int j = 0; j < 4; ++j) {
                int row = m0 + qr * 64 + mf * 16 + s4 * 4 + j;
#pragma unroll
                for (int nf = 0; nf < 4; ++nf) {
                    int e = qc * 64 + nf * 16 + r16;
                    if (e < INP)
                        __builtin_nontemporal_store(
                            acc[mf][nf][j],
                            &outp[((size_t)row * TT + (t - 1)) * INP + e]);
                }
            }
    }
}

// ---------------- launch ----------------
extern "C" void kernel_launch(void* const* d_in, const int* in_sizes, int n_in,
                              void* d_out, int out_size, void* d_ws, size_t ws_size,
                              hipStream_t stream)
{
    const float* x    = (const float*)d_in[0];
    const float* Wih  = (const float*)d_in[1];
    const float* Whh  = (const float*)d_in[2];
    const float* bih  = (const float*)d_in[3];
    const float* bhh  = (const float*)d_in[4];
    const float* Wlin = (const float*)d_in[5];
    const float* blin = (const float*)d_in[6];
    float* out = (float*)d_out;

    char* ws = (char*)d_ws;
    u16* hb0     = (u16*)(ws);                     //  8,388,608 B
    u16* hb1     = (u16*)(ws +  8388608);          //  8,388,608 B
    u16* xpad    = (u16*)(ws + 16777216);          //  5,242,880 B (20 t-slots)
    u16* wperm   = (u16*)(ws + 22020096);          //  8,650,752 B (4224 x 1024)
    u16* wxperm  = (u16*)(ws + 30670848);          //    270,336 B (4224 x 32)
    float* bias  = (float*)(ws + 30941184);        //     16,384 B

    float* h_fin = out + (size_t)BB * TT * INP;    // h_fin region
    float* c_buf = h_fin + (size_t)BB * HH;        // c_fin region = c state

    hipMemsetAsync(hb0, 0, (size_t)BB * HH * sizeof(u16), stream);
    hipMemsetAsync(c_buf, 0, (size_t)BB * HH * sizeof(float), stream);
    hipMemsetAsync((char*)xpad + (size_t)19 * BB * 32 * 2, 0, BB * 32 * 2, stream);

    prep_wperm<<<2112, 256, 0, stream>>>(Whh, Wlin, wperm);
    prep_wx<<<528, 256, 0, stream>>>(Wih, wxperm);
    prep_bias<<<16, 256, 0, stream>>>(bih, bhh, bias);
    prep_x<<<9728, 256, 0, stream>>>(x, xpad);

    for (int t = 0; t < TT; ++t) {
        const u16* hin = (t & 1) ? hb1 : hb0;
        u16* hout = (t & 1) ? hb0 : hb1;
        lstm_step<<<1056, 256, 0, stream>>>(
            hin, hout, c_buf, wperm, wxperm, bias, xpad, blin, out,
            h_fin, t, (t == TT - 1) ? 1 : 0, 0);
    }
    // tail: out_18 = h_19 @ W_lin^T + b_lin  (h_19 is in hb1 after t=18)
    lstm_step<<<32, 256, 0, stream>>>(
        hb1, hb0, c_buf, wperm, wxperm, bias, xpad, blin, out,
        h_fin, TT, 0, 1);
}